// Round 1
// baseline (956.829 us; speedup 1.0000x reference)
//
#include <hip/hip_runtime.h>

// ---------------------------------------------------------------------------
// ResidualAttentionBlock forward on MI355X (gfx950).
// x:[1025,4,1024] fp32. Outputs: x_out [1025,4,1024] fp32, attn [4,16,1025,1025] fp32.
// All GEMMs in bf16 MFMA (16x16x32), fp32 accumulate. Verified layouts per guide:
//   A/B frag: [idx=lane&15][k=quad*8+j] ; C/D: col=lane&15, row=quad*4+reg.
// ---------------------------------------------------------------------------

typedef unsigned short ushort_t;
typedef __bf16 bf16x8 __attribute__((ext_vector_type(8)));
typedef float f32x4 __attribute__((ext_vector_type(4)));

#define SEQ_N   1025
#define CMODEL  1024
#define NHEAD   16
#define DH      64
#define TTOK    4100            // 1025*4 tokens
#define MP      4224            // tokens padded to 33*128
#define NPAD    1152            // seq padded to 9*128
#define BH      64              // 4*16 (batch*heads)

__device__ __forceinline__ ushort_t f2bf(float f) {
  union { float f; unsigned u; } v; v.f = f;
  unsigned r = v.u + 0x7fffu + ((v.u >> 16) & 1u);   // RNE
  return (ushort_t)(r >> 16);
}

__device__ __forceinline__ void gl_lds16(const void* g, void* s) {
  __builtin_amdgcn_global_load_lds(
      (const __attribute__((address_space(1))) unsigned int*)g,
      (__attribute__((address_space(3))) unsigned int*)s, 16, 0, 0);
}

// --------------------------- fp32 -> bf16 convert ---------------------------
__global__ void cvt_bf(const float* __restrict__ src, ushort_t* __restrict__ dst, int n) {
  int i = (blockIdx.x * 256 + threadIdx.x) * 4;
  if (i >= n) return;
  float4 f = *(const float4*)(src + i);
  dst[i + 0] = f2bf(f.x);
  dst[i + 1] = f2bf(f.y);
  dst[i + 2] = f2bf(f.z);
  dst[i + 3] = f2bf(f.w);
}

// --------------------------- LayerNorm (fp32 in, bf16 out) ------------------
__global__ __launch_bounds__(256)
void ln_bf(const float* __restrict__ xin, const float* __restrict__ g,
           const float* __restrict__ bb, ushort_t* __restrict__ out) {
  const int t = blockIdx.x;
  const float* row = xin + (size_t)t * CMODEL;
  const int base = threadIdx.x * 4;
  const float4 v = *(const float4*)(row + base);
  float s = v.x + v.y + v.z + v.w;
  float q = v.x * v.x + v.y * v.y + v.z * v.z + v.w * v.w;
#pragma unroll
  for (int off = 32; off > 0; off >>= 1) {
    s += __shfl_down(s, off);
    q += __shfl_down(q, off);
  }
  __shared__ float sh[8];
  const int wave = threadIdx.x >> 6, lane = threadIdx.x & 63;
  if (lane == 0) { sh[wave] = s; sh[4 + wave] = q; }
  __syncthreads();
  if (threadIdx.x == 0) {
    const float ts = sh[0] + sh[1] + sh[2] + sh[3];
    const float tq = sh[4] + sh[5] + sh[6] + sh[7];
    const float mean = ts * (1.f / CMODEL);
    const float var = tq * (1.f / CMODEL) - mean * mean;
    sh[0] = mean; sh[1] = rsqrtf(var + 1e-5f);
  }
  __syncthreads();
  const float mean = sh[0], rstd = sh[1];
  const float4 gg = *(const float4*)(g + base);
  const float4 bv = *(const float4*)(bb + base);
  ushort_t* orow = out + (size_t)t * CMODEL;
  orow[base + 0] = f2bf((v.x - mean) * rstd * gg.x + bv.x);
  orow[base + 1] = f2bf((v.y - mean) * rstd * gg.y + bv.y);
  orow[base + 2] = f2bf((v.z - mean) * rstd * gg.z + bv.z);
  orow[base + 3] = f2bf((v.w - mean) * rstd * gg.w + bv.w);
}

// --------------------------- causal softmax (in-place, fp32) ----------------
__global__ __launch_bounds__(256)
void softmax_k(float* __restrict__ attn) {
  const int i = blockIdx.x;        // row 0..1024
  const int bh = blockIdx.y;       // 0..63
  float* row = attn + (size_t)bh * ((size_t)SEQ_N * SEQ_N) + (size_t)i * SEQ_N;
  const int len = i + 1;
  const int tid = threadIdx.x;
  float lmax = -1e30f;
  for (int j = tid; j < len; j += 256) lmax = fmaxf(lmax, row[j]);
#pragma unroll
  for (int off = 32; off > 0; off >>= 1) lmax = fmaxf(lmax, __shfl_down(lmax, off));
  __shared__ float sh[8];
  const int wave = tid >> 6, lane = tid & 63;
  if (lane == 0) sh[wave] = lmax;
  __syncthreads();
  const float m = fmaxf(fmaxf(sh[0], sh[1]), fmaxf(sh[2], sh[3]));
  float lsum = 0.f;
  for (int j = tid; j < len; j += 256) lsum += __expf(row[j] - m);
#pragma unroll
  for (int off = 32; off > 0; off >>= 1) lsum += __shfl_down(lsum, off);
  if (lane == 0) sh[4 + wave] = lsum;
  __syncthreads();
  const float inv = 1.f / (sh[4] + sh[5] + sh[6] + sh[7]);
  for (int j = tid; j < len; j += 256) row[j] = __expf(row[j] - m) * inv;
  for (int j = len + tid; j < SEQ_N; j += 256) row[j] = 0.f;
}

// --------------------------- bf16 MFMA GEMM (C = A * B^T) -------------------
// A [M x K] row-major bf16 (lda), B [N x K] row-major bf16 (ldb).
// 128x128 tile, BK=32, 256 thr = 4 waves, wave = 64x64 (4x4 MFMA 16x16x32).
// EPI: 0=qkv scatter  1=attn logits  3=bias+residual->fp32  4=bias+quickgelu->bf16
template <int EPI>
__global__ __launch_bounds__(256)
void gemm_bt(const ushort_t* __restrict__ A, int lda, long long sAz,
             const ushort_t* __restrict__ B, int ldb, long long sBz,
             int K,
             const float* __restrict__ bias, const float* __restrict__ res,
             float* __restrict__ outf, ushort_t* __restrict__ outb,
             ushort_t* __restrict__ oq, ushort_t* __restrict__ ok,
             ushort_t* __restrict__ ovt) {
  if constexpr (EPI == 1) {
    if (blockIdx.x > blockIdx.y) return;   // fully-masked causal tile
  }
  __shared__ __align__(16) ushort_t lsA[128 * 32];
  __shared__ __align__(16) ushort_t lsB[128 * 32];
  const int tid = threadIdx.x;
  const int wave = tid >> 6, lane = tid & 63;
  const int lr = lane & 15, quad = lane >> 4;
  const int z = blockIdx.z;
  const ushort_t* Ab = A + (size_t)z * sAz;
  const ushort_t* Bb = B + (size_t)z * sBz;
  const int tM = blockIdx.y * 128, tN = blockIdx.x * 128;
  const int waveM = (wave >> 1) * 64, waveN = (wave & 1) * 64;

  f32x4 acc[4][4];
  const f32x4 z4 = {0.f, 0.f, 0.f, 0.f};
#pragma unroll
  for (int i = 0; i < 4; ++i)
#pragma unroll
    for (int j = 0; j < 4; ++j) acc[i][j] = z4;

  for (int k0 = 0; k0 < K; k0 += 32) {
    __syncthreads();
#pragma unroll
    for (int p = 0; p < 2; ++p) {
      const int idx = p * 256 + wave * 64 + lane;      // chunk 0..511 (16B each)
      const int row = idx >> 2, part = idx & 3;
      const int cb = (p * 256 + wave * 64) * 8;        // wave-uniform LDS base (ushorts)
      gl_lds16(Ab + (size_t)(tM + row) * lda + k0 + part * 8, lsA + cb);
      gl_lds16(Bb + (size_t)(tN + row) * ldb + k0 + part * 8, lsB + cb);
    }
    __syncthreads();
    bf16x8 af[4], bfr[4];
#pragma unroll
    for (int mi = 0; mi < 4; ++mi)
      af[mi] = *(const bf16x8*)(lsA + (waveM + mi * 16 + lr) * 32 + quad * 8);
#pragma unroll
    for (int ni = 0; ni < 4; ++ni)
      bfr[ni] = *(const bf16x8*)(lsB + (waveN + ni * 16 + lr) * 32 + quad * 8);
#pragma unroll
    for (int mi = 0; mi < 4; ++mi)
#pragma unroll
      for (int ni = 0; ni < 4; ++ni)
        acc[mi][ni] = __builtin_amdgcn_mfma_f32_16x16x32_bf16(af[mi], bfr[ni], acc[mi][ni], 0, 0, 0);
  }

#pragma unroll
  for (int mi = 0; mi < 4; ++mi) {
#pragma unroll
    for (int ni = 0; ni < 4; ++ni) {
#pragma unroll
      for (int r = 0; r < 4; ++r) {
        const int m = tM + waveM + mi * 16 + quad * 4 + r;
        const int n = tN + waveN + ni * 16 + lr;
        const float v = acc[mi][ni][r];
        if constexpr (EPI == 0) {                 // qkv: scatter to q/k/v^T (bf16)
          if (m < TTOK) {
            const int b_ = m & 3, ns = m >> 2;
            const int which = n >> 10, rem = n & 1023, h = rem >> 6, d = rem & 63;
            const int bh = b_ * NHEAD + h;
            const ushort_t bv = f2bf(v);
            if (which == 0)      oq[((size_t)bh * NPAD + ns) * DH + d] = bv;
            else if (which == 1) ok[((size_t)bh * NPAD + ns) * DH + d] = bv;
            else                 ovt[((size_t)bh * DH + d) * NPAD + ns] = bv;
          }
        } else if constexpr (EPI == 1) {          // attn logits (scaled) -> fp32
          if (m < SEQ_N && n < SEQ_N)
            outf[(size_t)z * ((size_t)SEQ_N * SEQ_N) + (size_t)m * SEQ_N + n] = v * 0.125f;
        } else if constexpr (EPI == 3) {          // + bias + residual -> fp32
          if (m < TTOK)
            outf[(size_t)m * CMODEL + n] = v + bias[n] + res[(size_t)m * CMODEL + n];
        } else if constexpr (EPI == 4) {          // + bias, quickGELU -> bf16
          if (m < TTOK) {
            const float zv = v + bias[n];
            outb[(size_t)m * 4096 + n] = f2bf(zv / (1.f + __expf(-1.702f * zv)));
          }
        }
      }
    }
  }
}

// --------------------------- PV: out = attn(fp32) * V ----------------------
// A = attn row-major [1025 x 1025] fp32 (manual bf16 staging w/ bounds->0),
// B = v^T [64 x NPAD] bf16. N tile = 128 (upper half zero B). Causal K-trim.
__global__ __launch_bounds__(256)
void gemm_pv(const float* __restrict__ attn, const ushort_t* __restrict__ vt,
             ushort_t* __restrict__ ao) {
  __shared__ __align__(16) ushort_t lsA[128 * 32];
  __shared__ __align__(16) ushort_t lsB[128 * 32];
  const int tid = threadIdx.x;
  const int wave = tid >> 6, lane = tid & 63;
  const int lr = lane & 15, quad = lane >> 4;
  const int z = blockIdx.z;
  const int tM = blockIdx.y * 128;
  const float* Ab = attn + (size_t)z * ((size_t)SEQ_N * SEQ_N);
  const ushort_t* Bb = vt + (size_t)z * DH * NPAD;
  const int waveM = (wave >> 1) * 64, waveN = (wave & 1) * 64;

  f32x4 acc[4][4];
  const f32x4 z4 = {0.f, 0.f, 0.f, 0.f};
#pragma unroll
  for (int i = 0; i < 4; ++i)
#pragma unroll
    for (int j = 0; j < 4; ++j) acc[i][j] = z4;

  const int kmax = tM + 128;                       // causal: P[i][j]==0 for j>i
  for (int k0 = 0; k0 < kmax; k0 += 32) {
    __syncthreads();
#pragma unroll
    for (int p = 0; p < 2; ++p) {
      const int idx = p * 256 + tid;               // chunk 0..511
      const int row = idx >> 2, part = idx & 3;
      const int gi = tM + row;
      union { ushort_t u[8]; uint4 v; } tu;
#pragma unroll
      for (int e = 0; e < 8; ++e) {
        const int j = k0 + part * 8 + e;
        float av = 0.f;
        if (gi < SEQ_N && j < SEQ_N) av = Ab[(size_t)gi * SEQ_N + j];
        tu.u[e] = f2bf(av);
      }
      *(uint4*)(lsA + (size_t)idx * 8) = tu.v;
      uint4 bv = {0u, 0u, 0u, 0u};
      if (row < DH) bv = *(const uint4*)(Bb + (size_t)row * NPAD + k0 + part * 8);
      *(uint4*)(lsB + (size_t)idx * 8) = bv;
    }
    __syncthreads();
    bf16x8 af[4], bfr[4];
#pragma unroll
    for (int mi = 0; mi < 4; ++mi)
      af[mi] = *(const bf16x8*)(lsA + (waveM + mi * 16 + lr) * 32 + quad * 8);
#pragma unroll
    for (int ni = 0; ni < 4; ++ni)
      bfr[ni] = *(const bf16x8*)(lsB + (waveN + ni * 16 + lr) * 32 + quad * 8);
#pragma unroll
    for (int mi = 0; mi < 4; ++mi)
#pragma unroll
      for (int ni = 0; ni < 4; ++ni)
        acc[mi][ni] = __builtin_amdgcn_mfma_f32_16x16x32_bf16(af[mi], bfr[ni], acc[mi][ni], 0, 0, 0);
  }

  const int b_ = z >> 4, h = z & 15;
#pragma unroll
  for (int mi = 0; mi < 4; ++mi) {
#pragma unroll
    for (int ni = 0; ni < 4; ++ni) {
#pragma unroll
      for (int r = 0; r < 4; ++r) {
        const int m = tM + waveM + mi * 16 + quad * 4 + r;
        const int n = waveN + ni * 16 + lr;
        if (m < SEQ_N && n < DH)
          ao[(size_t)(m * 4 + b_) * CMODEL + h * DH + n] = f2bf(acc[mi][ni][r]);
      }
    }
  }
}

// ---------------------------------------------------------------------------
extern "C" void kernel_launch(void* const* d_in, const int* in_sizes, int n_in,
                              void* d_out, int out_size, void* d_ws, size_t ws_size,
                              hipStream_t stream) {
  const float* x       = (const float*)d_in[0];
  const float* qkv_w   = (const float*)d_in[1];
  const float* proj_w  = (const float*)d_in[2];
  const float* proj_b  = (const float*)d_in[3];
  const float* ln1_g   = (const float*)d_in[4];
  const float* ln1_b   = (const float*)d_in[5];
  const float* ln2_g   = (const float*)d_in[6];
  const float* ln2_b   = (const float*)d_in[7];
  const float* fc_w    = (const float*)d_in[8];
  const float* fc_b    = (const float*)d_in[9];
  const float* cproj_w = (const float*)d_in[10];
  const float* cproj_b = (const float*)d_in[11];

  float* out_x = (float*)d_out;
  float* out_attn = out_x + (size_t)TTOK * CMODEL;   // 4,198,400 floats in

  char* p = (char*)d_ws;
  auto alloc = [&](size_t bytes) { char* r = p; p += (bytes + 255) & ~(size_t)255; return r; };
  ushort_t* ln1x  = (ushort_t*)alloc((size_t)MP * CMODEL * 2);
  ushort_t* wqkv  = (ushort_t*)alloc((size_t)3072 * 1024 * 2);
  ushort_t* wproj = (ushort_t*)alloc((size_t)1024 * 1024 * 2);
  ushort_t* wfc   = (ushort_t*)alloc((size_t)4096 * 1024 * 2);
  ushort_t* wcpr  = (ushort_t*)alloc((size_t)1024 * 4096 * 2);
  ushort_t* qb    = (ushort_t*)alloc((size_t)BH * NPAD * DH * 2);
  ushort_t* kb    = (ushort_t*)alloc((size_t)BH * NPAD * DH * 2);
  ushort_t* vtb   = (ushort_t*)alloc((size_t)BH * DH * NPAD * 2);
  ushort_t* aob   = (ushort_t*)alloc((size_t)MP * CMODEL * 2);
  float*    x1    = (float*)alloc((size_t)MP * CMODEL * 4);
  ushort_t* ln2x  = (ushort_t*)alloc((size_t)MP * CMODEL * 2);
  ushort_t* hb    = (ushort_t*)alloc((size_t)MP * 4096 * 2);
  (void)ws_size; (void)in_sizes; (void)n_in; (void)out_size;

  // weights -> bf16
  cvt_bf<<<3072, 256, 0, stream>>>(qkv_w, wqkv, 3072 * 1024);
  cvt_bf<<<1024, 256, 0, stream>>>(proj_w, wproj, 1024 * 1024);
  cvt_bf<<<4096, 256, 0, stream>>>(fc_w, wfc, 4096 * 1024);
  cvt_bf<<<4096, 256, 0, stream>>>(cproj_w, wcpr, 4096 * 1024);

  // ln1
  ln_bf<<<TTOK, 256, 0, stream>>>(x, ln1_g, ln1_b, ln1x);

  // qkv = ln1x @ qkv_w.T  -> scatter q/k/v^T bf16
  gemm_bt<0><<<dim3(24, 33, 1), 256, 0, stream>>>(ln1x, 1024, 0, wqkv, 1024, 0, 1024,
      nullptr, nullptr, nullptr, nullptr, qb, kb, vtb);

  // S = Q K^T * scale -> fp32 logits straight into attn output region
  gemm_bt<1><<<dim3(9, 9, BH), 256, 0, stream>>>(qb, 64, (long long)NPAD * DH,
      kb, 64, (long long)NPAD * DH, 64,
      nullptr, nullptr, out_attn, nullptr, nullptr, nullptr, nullptr);

  // causal softmax in-place (writes zeros above diagonal)
  softmax_k<<<dim3(SEQ_N, BH), 256, 0, stream>>>(out_attn);

  // O = P V  (reads fp32 attn, stages to bf16) -> attn-out bf16 [token, C]
  gemm_pv<<<dim3(1, 9, BH), 256, 0, stream>>>(out_attn, vtb, aob);

  // proj + bias + residual -> x1 fp32
  gemm_bt<3><<<dim3(8, 33, 1), 256, 0, stream>>>(aob, 1024, 0, wproj, 1024, 0, 1024,
      proj_b, x, x1, nullptr, nullptr, nullptr, nullptr);

  // ln2
  ln_bf<<<TTOK, 256, 0, stream>>>(x1, ln2_g, ln2_b, ln2x);

  // fc + bias + quickGELU -> bf16
  gemm_bt<4><<<dim3(32, 33, 1), 256, 0, stream>>>(ln2x, 1024, 0, wfc, 1024, 0, 1024,
      fc_b, nullptr, nullptr, hb, nullptr, nullptr, nullptr);

  // cproj + bias + residual -> final x output
  gemm_bt<3><<<dim3(8, 33, 1), 256, 0, stream>>>(hb, 4096, 0, wcpr, 4096, 0, 4096,
      cproj_b, x1, out_x, nullptr, nullptr, nullptr, nullptr);
}

// Round 3
// 851.115 us; speedup vs baseline: 1.1242x; 1.1242x over previous
//
#include <hip/hip_runtime.h>

// ---------------------------------------------------------------------------
// ResidualAttentionBlock forward on MI355X (gfx950).
// Round 3: fused causal attention (S -> softmax -> P-write -> PV) in one kernel.
// (Round 2 + compile fix: nontemporal store needs ext_vector_type, not float4.)
// ---------------------------------------------------------------------------

typedef unsigned short ushort_t;
typedef __bf16 bf16x8 __attribute__((ext_vector_type(8)));
typedef float f32x4 __attribute__((ext_vector_type(4)));

#define SEQ_N   1025
#define CMODEL  1024
#define NHEAD   16
#define DH      64
#define TTOK    4100            // 1025*4 tokens
#define MP      4224            // tokens padded to 33*128
#define NPAD    1152            // seq padded to 9*128
#define BH      64              // 4*16 (batch*heads)

__device__ __forceinline__ ushort_t f2bf(float f) {
  union { float f; unsigned u; } v; v.f = f;
  unsigned r = v.u + 0x7fffu + ((v.u >> 16) & 1u);   // RNE
  return (ushort_t)(r >> 16);
}

__device__ __forceinline__ void gl_lds16(const void* g, void* s) {
  __builtin_amdgcn_global_load_lds(
      (const __attribute__((address_space(1))) unsigned int*)g,
      (__attribute__((address_space(3))) unsigned int*)s, 16, 0, 0);
}

// --------------------------- fp32 -> bf16 convert ---------------------------
__global__ void cvt_bf(const float* __restrict__ src, ushort_t* __restrict__ dst, int n) {
  int i = (blockIdx.x * 256 + threadIdx.x) * 4;
  if (i >= n) return;
  float4 f = *(const float4*)(src + i);
  dst[i + 0] = f2bf(f.x);
  dst[i + 1] = f2bf(f.y);
  dst[i + 2] = f2bf(f.z);
  dst[i + 3] = f2bf(f.w);
}

// --------------------------- LayerNorm (fp32 in, bf16 out) ------------------
__global__ __launch_bounds__(256)
void ln_bf(const float* __restrict__ xin, const float* __restrict__ g,
           const float* __restrict__ bb, ushort_t* __restrict__ out) {
  const int t = blockIdx.x;
  const float* row = xin + (size_t)t * CMODEL;
  const int base = threadIdx.x * 4;
  const float4 v = *(const float4*)(row + base);
  float s = v.x + v.y + v.z + v.w;
  float q = v.x * v.x + v.y * v.y + v.z * v.z + v.w * v.w;
#pragma unroll
  for (int off = 32; off > 0; off >>= 1) {
    s += __shfl_down(s, off);
    q += __shfl_down(q, off);
  }
  __shared__ float sh[8];
  const int wave = threadIdx.x >> 6, lane = threadIdx.x & 63;
  if (lane == 0) { sh[wave] = s; sh[4 + wave] = q; }
  __syncthreads();
  if (threadIdx.x == 0) {
    const float ts = sh[0] + sh[1] + sh[2] + sh[3];
    const float tq = sh[4] + sh[5] + sh[6] + sh[7];
    const float mean = ts * (1.f / CMODEL);
    const float var = tq * (1.f / CMODEL) - mean * mean;
    sh[0] = mean; sh[1] = rsqrtf(var + 1e-5f);
  }
  __syncthreads();
  const float mean = sh[0], rstd = sh[1];
  const float4 gg = *(const float4*)(g + base);
  const float4 bv = *(const float4*)(bb + base);
  ushort_t* orow = out + (size_t)t * CMODEL;
  orow[base + 0] = f2bf((v.x - mean) * rstd * gg.x + bv.x);
  orow[base + 1] = f2bf((v.y - mean) * rstd * gg.y + bv.y);
  orow[base + 2] = f2bf((v.z - mean) * rstd * gg.z + bv.z);
  orow[base + 3] = f2bf((v.w - mean) * rstd * gg.w + bv.w);
}

// --------------------------- bf16 MFMA GEMM (C = A * B^T) -------------------
// EPI: 0=qkv scatter  3=bias+residual->fp32  4=bias+quickgelu->bf16
template <int EPI>
__global__ __launch_bounds__(256)
void gemm_bt(const ushort_t* __restrict__ A, int lda,
             const ushort_t* __restrict__ B, int ldb,
             int K,
             const float* __restrict__ bias, const float* __restrict__ res,
             float* __restrict__ outf, ushort_t* __restrict__ outb,
             ushort_t* __restrict__ oq, ushort_t* __restrict__ ok,
             ushort_t* __restrict__ ovt) {
  __shared__ __align__(16) ushort_t lsA[128 * 32];
  __shared__ __align__(16) ushort_t lsB[128 * 32];
  const int tid = threadIdx.x;
  const int wave = tid >> 6, lane = tid & 63;
  const int lr = lane & 15, quad = lane >> 4;
  const int tM = blockIdx.y * 128, tN = blockIdx.x * 128;
  const int waveM = (wave >> 1) * 64, waveN = (wave & 1) * 64;

  f32x4 acc[4][4];
  const f32x4 z4 = {0.f, 0.f, 0.f, 0.f};
#pragma unroll
  for (int i = 0; i < 4; ++i)
#pragma unroll
    for (int j = 0; j < 4; ++j) acc[i][j] = z4;

  for (int k0 = 0; k0 < K; k0 += 32) {
    __syncthreads();
#pragma unroll
    for (int p = 0; p < 2; ++p) {
      const int idx = p * 256 + wave * 64 + lane;      // chunk 0..511 (16B each)
      const int row = idx >> 2, part = idx & 3;
      const int cb = (p * 256 + wave * 64) * 8;        // wave-uniform LDS base
      gl_lds16(A + (size_t)(tM + row) * lda + k0 + part * 8, lsA + cb);
      gl_lds16(B + (size_t)(tN + row) * ldb + k0 + part * 8, lsB + cb);
    }
    __syncthreads();
    bf16x8 af[4], bfr[4];
#pragma unroll
    for (int mi = 0; mi < 4; ++mi)
      af[mi] = *(const bf16x8*)(lsA + (waveM + mi * 16 + lr) * 32 + quad * 8);
#pragma unroll
    for (int ni = 0; ni < 4; ++ni)
      bfr[ni] = *(const bf16x8*)(lsB + (waveN + ni * 16 + lr) * 32 + quad * 8);
#pragma unroll
    for (int mi = 0; mi < 4; ++mi)
#pragma unroll
      for (int ni = 0; ni < 4; ++ni)
        acc[mi][ni] = __builtin_amdgcn_mfma_f32_16x16x32_bf16(af[mi], bfr[ni], acc[mi][ni], 0, 0, 0);
  }

#pragma unroll
  for (int mi = 0; mi < 4; ++mi) {
#pragma unroll
    for (int ni = 0; ni < 4; ++ni) {
#pragma unroll
      for (int r = 0; r < 4; ++r) {
        const int m = tM + waveM + mi * 16 + quad * 4 + r;
        const int n = tN + waveN + ni * 16 + lr;
        const float v = acc[mi][ni][r];
        if constexpr (EPI == 0) {                 // qkv: scatter to q/k/v^T (bf16)
          if (m < TTOK) {
            const int b_ = m & 3, ns = m >> 2;
            const int which = n >> 10, rem = n & 1023, h = rem >> 6, d = rem & 63;
            const int bh = b_ * NHEAD + h;
            const ushort_t bv = f2bf(v);
            if (which == 0)      oq[((size_t)bh * NPAD + ns) * DH + d] = bv;
            else if (which == 1) ok[((size_t)bh * NPAD + ns) * DH + d] = bv;
            else                 ovt[((size_t)bh * DH + d) * NPAD + ns] = bv;
          }
        } else if constexpr (EPI == 3) {          // + bias + residual -> fp32
          if (m < TTOK)
            outf[(size_t)m * CMODEL + n] = v + bias[n] + res[(size_t)m * CMODEL + n];
        } else if constexpr (EPI == 4) {          // + bias, quickGELU -> bf16
          if (m < TTOK) {
            const float zv = v + bias[n];
            outb[(size_t)m * 4096 + n] = f2bf(zv / (1.f + __expf(-1.702f * zv)));
          }
        }
      }
    }
  }
}

// --------------------------- fused causal attention -------------------------
// Grid (bh=64, it=9). Block = 256 thr. Per block: 128 Q rows of one head.
// Pass 1: S=QK^T, accumulate row sums of exp(S*scale) (no max; |S| small).
// Pass 2: recompute S, P=exp*inv_l, write P (fp32, nt) to attn out, P->LDS bf16,
//         O += P*V via MFMA. Then write O and zero the strictly-upper region.
__global__ __launch_bounds__(256)
void attn_fused(const ushort_t* __restrict__ qb, const ushort_t* __restrict__ kb,
                const ushort_t* __restrict__ vtb, float* __restrict__ attn,
                ushort_t* __restrict__ ao) {
  __shared__ __align__(16) char smem[16384 + 17408 + 34816 + 1024 + 512];
  ushort_t* lsK  = (ushort_t*)smem;                         // 2x [128][32] sub-tiles
  ushort_t* lsQV = (ushort_t*)(smem + 16384);               // Q staging, then V [64][136]
  ushort_t* lsP  = (ushort_t*)(smem + 16384 + 17408);       // P [128][136]
  float*    lpart = (float*)(smem + 16384 + 17408 + 34816); // [2][128]
  float*    linvs = lpart + 256;                            // [128]

  const int bh = blockIdx.x;
  const int iT = 8 - blockIdx.y;          // heaviest tiles dispatch first
  const int tM = iT * 128;
  const int tid = threadIdx.x;
  const int wave = tid >> 6, lane = tid & 63;
  const int lr = lane & 15, quad = lane >> 4;
  const int waveM = (wave >> 1) * 64, waveN = (wave & 1) * 64;

  const ushort_t* Qg = qb + (size_t)bh * NPAD * DH;
  const ushort_t* Kg = kb + (size_t)bh * NPAD * DH;
  const ushort_t* Vg = vtb + (size_t)bh * DH * NPAD;
  float* attn_h = attn + (size_t)bh * ((size_t)SEQ_N * SEQ_N);

  // ---- stage Q once, keep as register fragments ----
#pragma unroll
  for (int p = 0; p < 4; ++p) {
    const int c = p * 256 + wave * 64 + lane;
    const int ks = c >> 9, n = (c >> 2) & 127, part = c & 3;
    gl_lds16(Qg + (size_t)(tM + n) * DH + ks * 32 + part * 8,
             lsQV + (size_t)(p * 256 + wave * 64) * 8);
  }
  __syncthreads();
  bf16x8 aq[4][2];
#pragma unroll
  for (int mi = 0; mi < 4; ++mi)
#pragma unroll
    for (int ks = 0; ks < 2; ++ks)
      aq[mi][ks] = *(const bf16x8*)(lsQV + ks * 4096 + (waveM + mi * 16 + lr) * 32 + quad * 8);
  __syncthreads();

  f32x4 acc[4][4];
  const f32x4 z4 = {0.f, 0.f, 0.f, 0.f};

  // ---- pass 1: row sums of exp ----
  float lsum[4][4];
#pragma unroll
  for (int mi = 0; mi < 4; ++mi)
#pragma unroll
    for (int r = 0; r < 4; ++r) lsum[mi][r] = 0.f;

  for (int j = 0; j <= iT; ++j) {
    __syncthreads();
#pragma unroll
    for (int p = 0; p < 4; ++p) {
      const int c = p * 256 + wave * 64 + lane;
      const int ks = c >> 9, n = (c >> 2) & 127, part = c & 3;
      gl_lds16(Kg + (size_t)(j * 128 + n) * DH + ks * 32 + part * 8,
               lsK + (size_t)(p * 256 + wave * 64) * 8);
    }
    __syncthreads();
#pragma unroll
    for (int mi = 0; mi < 4; ++mi)
#pragma unroll
      for (int ni = 0; ni < 4; ++ni) acc[mi][ni] = z4;
#pragma unroll
    for (int ks = 0; ks < 2; ++ks) {
      bf16x8 bk[4];
#pragma unroll
      for (int ni = 0; ni < 4; ++ni)
        bk[ni] = *(const bf16x8*)(lsK + ks * 4096 + (waveN + ni * 16 + lr) * 32 + quad * 8);
#pragma unroll
      for (int mi = 0; mi < 4; ++mi)
#pragma unroll
        for (int ni = 0; ni < 4; ++ni)
          acc[mi][ni] = __builtin_amdgcn_mfma_f32_16x16x32_bf16(aq[mi][ks], bk[ni], acc[mi][ni], 0, 0, 0);
    }
#pragma unroll
    for (int mi = 0; mi < 4; ++mi)
#pragma unroll
      for (int ni = 0; ni < 4; ++ni)
#pragma unroll
        for (int r = 0; r < 4; ++r) {
          const int row = tM + waveM + mi * 16 + quad * 4 + r;
          const int col = j * 128 + waveN + ni * 16 + lr;
          if (col <= row) lsum[mi][r] += __expf(acc[mi][ni][r] * 0.125f);
        }
  }
  // reduce across the 16 col-lanes, combine wave halves via LDS
#pragma unroll
  for (int mi = 0; mi < 4; ++mi)
#pragma unroll
    for (int r = 0; r < 4; ++r) {
      float s = lsum[mi][r];
      s += __shfl_xor(s, 1); s += __shfl_xor(s, 2);
      s += __shfl_xor(s, 4); s += __shfl_xor(s, 8);
      lsum[mi][r] = s;
    }
  if (lr == 0) {
    const int wx = wave & 1;
#pragma unroll
    for (int mi = 0; mi < 4; ++mi)
#pragma unroll
      for (int r = 0; r < 4; ++r)
        lpart[wx * 128 + waveM + mi * 16 + quad * 4 + r] = lsum[mi][r];
  }
  __syncthreads();
  if (tid < 128) linvs[tid] = 1.0f / (lpart[tid] + lpart[128 + tid]);
  __syncthreads();
  float linv[4][4];
#pragma unroll
  for (int mi = 0; mi < 4; ++mi)
#pragma unroll
    for (int r = 0; r < 4; ++r)
      linv[mi][r] = linvs[waveM + mi * 16 + quad * 4 + r];

  // ---- pass 2: P write + PV ----
  f32x4 oacc[2][4];
#pragma unroll
  for (int i = 0; i < 2; ++i)
#pragma unroll
    for (int j = 0; j < 4; ++j) oacc[i][j] = z4;
  const int prow = wave * 32;             // O rows owned by this wave

  for (int j = 0; j <= iT; ++j) {
    __syncthreads();
#pragma unroll
    for (int p = 0; p < 4; ++p) {
      const int c = p * 256 + wave * 64 + lane;
      const int ks = c >> 9, n = (c >> 2) & 127, part = c & 3;
      gl_lds16(Kg + (size_t)(j * 128 + n) * DH + ks * 32 + part * 8,
               lsK + (size_t)(p * 256 + wave * 64) * 8);
    }
    // V -> padded LDS [64][136] (manual; padding breaks bank pathology)
#pragma unroll
    for (int p = 0; p < 4; ++p) {
      const int c = p * 256 + tid;
      const int n = c >> 4, klc = c & 15;
      const uint4 v = *(const uint4*)(Vg + (size_t)n * NPAD + j * 128 + klc * 8);
      *(uint4*)(lsQV + (size_t)n * 136 + klc * 8) = v;
    }
    __syncthreads();
#pragma unroll
    for (int mi = 0; mi < 4; ++mi)
#pragma unroll
      for (int ni = 0; ni < 4; ++ni) acc[mi][ni] = z4;
#pragma unroll
    for (int ks = 0; ks < 2; ++ks) {
      bf16x8 bk[4];
#pragma unroll
      for (int ni = 0; ni < 4; ++ni)
        bk[ni] = *(const bf16x8*)(lsK + ks * 4096 + (waveN + ni * 16 + lr) * 32 + quad * 8);
#pragma unroll
      for (int mi = 0; mi < 4; ++mi)
#pragma unroll
        for (int ni = 0; ni < 4; ++ni)
          acc[mi][ni] = __builtin_amdgcn_mfma_f32_16x16x32_bf16(aq[mi][ks], bk[ni], acc[mi][ni], 0, 0, 0);
    }
#pragma unroll
    for (int mi = 0; mi < 4; ++mi)
#pragma unroll
      for (int ni = 0; ni < 4; ++ni)
#pragma unroll
        for (int r = 0; r < 4; ++r) {
          const int rowl = waveM + mi * 16 + quad * 4 + r;
          const int coll = waveN + ni * 16 + lr;
          const int row = tM + rowl;
          const int col = j * 128 + coll;
          const float pv = (col <= row) ? __expf(acc[mi][ni][r] * 0.125f) * linv[mi][r] : 0.f;
          if (row < SEQ_N && col < SEQ_N)
            __builtin_nontemporal_store(pv, attn_h + (size_t)row * SEQ_N + col);
          lsP[(size_t)rowl * 136 + coll] = f2bf(pv);
        }
    __syncthreads();
#pragma unroll
    for (int ks = 0; ks < 4; ++ks) {
      bf16x8 ap[2], bv[4];
#pragma unroll
      for (int mi2 = 0; mi2 < 2; ++mi2)
        ap[mi2] = *(const bf16x8*)(lsP + (size_t)(prow + mi2 * 16 + lr) * 136 + ks * 32 + quad * 8);
#pragma unroll
      for (int ni = 0; ni < 4; ++ni)
        bv[ni] = *(const bf16x8*)(lsQV + (size_t)(ni * 16 + lr) * 136 + ks * 32 + quad * 8);
#pragma unroll
      for (int mi2 = 0; mi2 < 2; ++mi2)
#pragma unroll
        for (int ni = 0; ni < 4; ++ni)
          oacc[mi2][ni] = __builtin_amdgcn_mfma_f32_16x16x32_bf16(ap[mi2], bv[ni], oacc[mi2][ni], 0, 0, 0);
    }
  }

  // ---- write O (bf16, token-major for proj GEMM) ----
  const int b_ = bh >> 4, h = bh & 15;
#pragma unroll
  for (int mi2 = 0; mi2 < 2; ++mi2)
#pragma unroll
    for (int ni = 0; ni < 4; ++ni)
#pragma unroll
      for (int r = 0; r < 4; ++r) {
        const int row = tM + prow + mi2 * 16 + quad * 4 + r;
        const int d = ni * 16 + lr;
        if (row < SEQ_N)
          ao[((size_t)row * 4 + b_) * CMODEL + h * DH + d] = f2bf(oacc[mi2][ni][r]);
      }

  // ---- zero strictly-upper attn region for these rows ----
  const int c0 = tM + 128;
  if (c0 <= 1024) {
    const int width = 1025 - c0;
    for (int r = wave; r < 128; r += 4) {
      float* rp = attn_h + (size_t)(tM + r) * SEQ_N + c0;
      int pre = ((16 - (int)(((uintptr_t)rp) & 15)) >> 2) & 3;
      if (pre > width) pre = width;
      for (int c = lane; c < pre; c += 64) rp[c] = 0.f;
      const int body = (width - pre) >> 2;
      f32x4* bp = (f32x4*)(rp + pre);
      const f32x4 zf4 = {0.f, 0.f, 0.f, 0.f};
      for (int c = lane; c < body; c += 64) __builtin_nontemporal_store(zf4, bp + c);
      for (int c = pre + body * 4 + lane; c < width; c += 64) rp[c] = 0.f;
    }
  }
}

// ---------------------------------------------------------------------------
extern "C" void kernel_launch(void* const* d_in, const int* in_sizes, int n_in,
                              void* d_out, int out_size, void* d_ws, size_t ws_size,
                              hipStream_t stream) {
  const float* x       = (const float*)d_in[0];
  const float* qkv_w   = (const float*)d_in[1];
  const float* proj_w  = (const float*)d_in[2];
  const float* proj_b  = (const float*)d_in[3];
  const float* ln1_g   = (const float*)d_in[4];
  const float* ln1_b   = (const float*)d_in[5];
  const float* ln2_g   = (const float*)d_in[6];
  const float* ln2_b   = (const float*)d_in[7];
  const float* fc_w    = (const float*)d_in[8];
  const float* fc_b    = (const float*)d_in[9];
  const float* cproj_w = (const float*)d_in[10];
  const float* cproj_b = (const float*)d_in[11];

  float* out_x = (float*)d_out;
  float* out_attn = out_x + (size_t)TTOK * CMODEL;

  char* p = (char*)d_ws;
  auto alloc = [&](size_t bytes) { char* r = p; p += (bytes + 255) & ~(size_t)255; return r; };
  ushort_t* ln1x  = (ushort_t*)alloc((size_t)MP * CMODEL * 2);
  ushort_t* wqkv  = (ushort_t*)alloc((size_t)3072 * 1024 * 2);
  ushort_t* wproj = (ushort_t*)alloc((size_t)1024 * 1024 * 2);
  ushort_t* wfc   = (ushort_t*)alloc((size_t)4096 * 1024 * 2);
  ushort_t* wcpr  = (ushort_t*)alloc((size_t)1024 * 4096 * 2);
  ushort_t* qb    = (ushort_t*)alloc((size_t)BH * NPAD * DH * 2);
  ushort_t* kb    = (ushort_t*)alloc((size_t)BH * NPAD * DH * 2);
  ushort_t* vtb   = (ushort_t*)alloc((size_t)BH * DH * NPAD * 2);
  ushort_t* aob   = (ushort_t*)alloc((size_t)MP * CMODEL * 2);
  float*    x1    = (float*)alloc((size_t)MP * CMODEL * 4);
  ushort_t* ln2x  = (ushort_t*)alloc((size_t)MP * CMODEL * 2);
  ushort_t* hb    = (ushort_t*)alloc((size_t)MP * 4096 * 2);
  (void)ws_size; (void)in_sizes; (void)n_in; (void)out_size;

  // weights -> bf16
  cvt_bf<<<3072, 256, 0, stream>>>(qkv_w, wqkv, 3072 * 1024);
  cvt_bf<<<1024, 256, 0, stream>>>(proj_w, wproj, 1024 * 1024);
  cvt_bf<<<4096, 256, 0, stream>>>(fc_w, wfc, 4096 * 1024);
  cvt_bf<<<4096, 256, 0, stream>>>(cproj_w, wcpr, 4096 * 1024);

  // ln1
  ln_bf<<<TTOK, 256, 0, stream>>>(x, ln1_g, ln1_b, ln1x);

  // qkv = ln1x @ qkv_w.T  -> scatter q/k/v^T bf16
  gemm_bt<0><<<dim3(24, 33, 1), 256, 0, stream>>>(ln1x, 1024, wqkv, 1024, 1024,
      nullptr, nullptr, nullptr, nullptr, qb, kb, vtb);

  // fused attention: logits+softmax+attn-write+PV
  attn_fused<<<dim3(64, 9), 256, 0, stream>>>(qb, kb, vtb, out_attn, aob);

  // proj + bias + residual -> x1 fp32
  gemm_bt<3><<<dim3(8, 33, 1), 256, 0, stream>>>(aob, 1024, wproj, 1024, 1024,
      proj_b, x, x1, nullptr, nullptr, nullptr, nullptr);

  // ln2
  ln_bf<<<TTOK, 256, 0, stream>>>(x1, ln2_g, ln2_b, ln2x);

  // fc + bias + quickGELU -> bf16
  gemm_bt<4><<<dim3(32, 33, 1), 256, 0, stream>>>(ln2x, 1024, wfc, 1024, 1024,
      fc_b, nullptr, nullptr, hb, nullptr, nullptr, nullptr);

  // cproj + bias + residual -> final x output
  gemm_bt<3><<<dim3(8, 33, 1), 256, 0, stream>>>(hb, 4096, wcpr, 4096, 4096,
      cproj_b, x1, out_x, nullptr, nullptr, nullptr, nullptr);
}

// Round 4
// 781.721 us; speedup vs baseline: 1.2240x; 1.0888x over previous
//
#include <hip/hip_runtime.h>

// ---------------------------------------------------------------------------
// ResidualAttentionBlock forward on MI355X (gfx950).
// Round 4: fused attention with coalesced P-write (LDS readback) and
// LDS union (K/P share a region) -> 51.5 KB/block -> 3 blocks/CU.
// ---------------------------------------------------------------------------

typedef unsigned short ushort_t;
typedef __bf16 bf16x8 __attribute__((ext_vector_type(8)));
typedef float f32x4 __attribute__((ext_vector_type(4)));

#define SEQ_N   1025
#define CMODEL  1024
#define NHEAD   16
#define DH      64
#define TTOK    4100            // 1025*4 tokens
#define MP      4224            // tokens padded to 33*128
#define NPAD    1152            // seq padded to 9*128
#define BH      64              // 4*16 (batch*heads)

__device__ __forceinline__ ushort_t f2bf(float f) {
  union { float f; unsigned u; } v; v.f = f;
  unsigned r = v.u + 0x7fffu + ((v.u >> 16) & 1u);   // RNE
  return (ushort_t)(r >> 16);
}

__device__ __forceinline__ void gl_lds16(const void* g, void* s) {
  __builtin_amdgcn_global_load_lds(
      (const __attribute__((address_space(1))) unsigned int*)g,
      (__attribute__((address_space(3))) unsigned int*)s, 16, 0, 0);
}

// --------------------------- fp32 -> bf16 convert ---------------------------
__global__ void cvt_bf(const float* __restrict__ src, ushort_t* __restrict__ dst, int n) {
  int i = (blockIdx.x * 256 + threadIdx.x) * 4;
  if (i >= n) return;
  float4 f = *(const float4*)(src + i);
  dst[i + 0] = f2bf(f.x);
  dst[i + 1] = f2bf(f.y);
  dst[i + 2] = f2bf(f.z);
  dst[i + 3] = f2bf(f.w);
}

// --------------------------- LayerNorm (fp32 in, bf16 out) ------------------
__global__ __launch_bounds__(256)
void ln_bf(const float* __restrict__ xin, const float* __restrict__ g,
           const float* __restrict__ bb, ushort_t* __restrict__ out) {
  const int t = blockIdx.x;
  const float* row = xin + (size_t)t * CMODEL;
  const int base = threadIdx.x * 4;
  const float4 v = *(const float4*)(row + base);
  float s = v.x + v.y + v.z + v.w;
  float q = v.x * v.x + v.y * v.y + v.z * v.z + v.w * v.w;
#pragma unroll
  for (int off = 32; off > 0; off >>= 1) {
    s += __shfl_down(s, off);
    q += __shfl_down(q, off);
  }
  __shared__ float sh[8];
  const int wave = threadIdx.x >> 6, lane = threadIdx.x & 63;
  if (lane == 0) { sh[wave] = s; sh[4 + wave] = q; }
  __syncthreads();
  if (threadIdx.x == 0) {
    const float ts = sh[0] + sh[1] + sh[2] + sh[3];
    const float tq = sh[4] + sh[5] + sh[6] + sh[7];
    const float mean = ts * (1.f / CMODEL);
    const float var = tq * (1.f / CMODEL) - mean * mean;
    sh[0] = mean; sh[1] = rsqrtf(var + 1e-5f);
  }
  __syncthreads();
  const float mean = sh[0], rstd = sh[1];
  const float4 gg = *(const float4*)(g + base);
  const float4 bv = *(const float4*)(bb + base);
  ushort_t* orow = out + (size_t)t * CMODEL;
  orow[base + 0] = f2bf((v.x - mean) * rstd * gg.x + bv.x);
  orow[base + 1] = f2bf((v.y - mean) * rstd * gg.y + bv.y);
  orow[base + 2] = f2bf((v.z - mean) * rstd * gg.z + bv.z);
  orow[base + 3] = f2bf((v.w - mean) * rstd * gg.w + bv.w);
}

// --------------------------- bf16 MFMA GEMM (C = A * B^T) -------------------
// EPI: 0=qkv scatter  3=bias+residual->fp32  4=bias+quickgelu->bf16
template <int EPI>
__global__ __launch_bounds__(256)
void gemm_bt(const ushort_t* __restrict__ A, int lda,
             const ushort_t* __restrict__ B, int ldb,
             int K,
             const float* __restrict__ bias, const float* __restrict__ res,
             float* __restrict__ outf, ushort_t* __restrict__ outb,
             ushort_t* __restrict__ oq, ushort_t* __restrict__ ok,
             ushort_t* __restrict__ ovt) {
  __shared__ __align__(16) ushort_t lsA[128 * 32];
  __shared__ __align__(16) ushort_t lsB[128 * 32];
  const int tid = threadIdx.x;
  const int wave = tid >> 6, lane = tid & 63;
  const int lr = lane & 15, quad = lane >> 4;
  const int tM = blockIdx.y * 128, tN = blockIdx.x * 128;
  const int waveM = (wave >> 1) * 64, waveN = (wave & 1) * 64;

  f32x4 acc[4][4];
  const f32x4 z4 = {0.f, 0.f, 0.f, 0.f};
#pragma unroll
  for (int i = 0; i < 4; ++i)
#pragma unroll
    for (int j = 0; j < 4; ++j) acc[i][j] = z4;

  for (int k0 = 0; k0 < K; k0 += 32) {
    __syncthreads();
#pragma unroll
    for (int p = 0; p < 2; ++p) {
      const int idx = p * 256 + wave * 64 + lane;      // chunk 0..511 (16B each)
      const int row = idx >> 2, part = idx & 3;
      const int cb = (p * 256 + wave * 64) * 8;        // wave-uniform LDS base
      gl_lds16(A + (size_t)(tM + row) * lda + k0 + part * 8, lsA + cb);
      gl_lds16(B + (size_t)(tN + row) * ldb + k0 + part * 8, lsB + cb);
    }
    __syncthreads();
    bf16x8 af[4], bfr[4];
#pragma unroll
    for (int mi = 0; mi < 4; ++mi)
      af[mi] = *(const bf16x8*)(lsA + (waveM + mi * 16 + lr) * 32 + quad * 8);
#pragma unroll
    for (int ni = 0; ni < 4; ++ni)
      bfr[ni] = *(const bf16x8*)(lsB + (waveN + ni * 16 + lr) * 32 + quad * 8);
#pragma unroll
    for (int mi = 0; mi < 4; ++mi)
#pragma unroll
      for (int ni = 0; ni < 4; ++ni)
        acc[mi][ni] = __builtin_amdgcn_mfma_f32_16x16x32_bf16(af[mi], bfr[ni], acc[mi][ni], 0, 0, 0);
  }

#pragma unroll
  for (int mi = 0; mi < 4; ++mi) {
#pragma unroll
    for (int ni = 0; ni < 4; ++ni) {
#pragma unroll
      for (int r = 0; r < 4; ++r) {
        const int m = tM + waveM + mi * 16 + quad * 4 + r;
        const int n = tN + waveN + ni * 16 + lr;
        const float v = acc[mi][ni][r];
        if constexpr (EPI == 0) {                 // qkv: scatter to q/k/v^T (bf16)
          if (m < TTOK) {
            const int b_ = m & 3, ns = m >> 2;
            const int which = n >> 10, rem = n & 1023, h = rem >> 6, d = rem & 63;
            const int bh = b_ * NHEAD + h;
            const ushort_t bv = f2bf(v);
            if (which == 0)      oq[((size_t)bh * NPAD + ns) * DH + d] = bv;
            else if (which == 1) ok[((size_t)bh * NPAD + ns) * DH + d] = bv;
            else                 ovt[((size_t)bh * DH + d) * NPAD + ns] = bv;
          }
        } else if constexpr (EPI == 3) {          // + bias + residual -> fp32
          if (m < TTOK)
            outf[(size_t)m * CMODEL + n] = v + bias[n] + res[(size_t)m * CMODEL + n];
        } else if constexpr (EPI == 4) {          // + bias, quickGELU -> bf16
          if (m < TTOK) {
            const float zv = v + bias[n];
            outb[(size_t)m * 4096 + n] = f2bf(zv / (1.f + __expf(-1.702f * zv)));
          }
        }
      }
    }
  }
}

// --------------------------- fused causal attention -------------------------
// Grid (bh=64, it=9). Block = 256 thr. Per block: 128 Q rows of one head.
// LDS: region0 (34816B) = K staging UNION P tile UNION lpart;
//      region1 (17408B) = Q staging, then V [64][136]; region2 = linvs (512B).
// Pass 1: S=QK^T, accumulate row sums of exp(S*scale).
// Pass 2: S again -> P=exp*inv -> lsP (bf16) -> PV MFMA + coalesced nt P-write.
__global__ __launch_bounds__(256)
void attn_fused(const ushort_t* __restrict__ qb, const ushort_t* __restrict__ kb,
                const ushort_t* __restrict__ vtb, float* __restrict__ attn,
                ushort_t* __restrict__ ao) {
  __shared__ __align__(16) char smem[34816 + 17408 + 512];
  ushort_t* lsK  = (ushort_t*)smem;                 // K staging (pass1/2)
  ushort_t* lsP  = (ushort_t*)smem;                 // P [128][136] (union w/ lsK)
  float*    lpart = (float*)smem;                   // [2][128] (pass1-end only)
  ushort_t* lsQV = (ushort_t*)(smem + 34816);       // Q staging, then V [64][136]
  float*    linvs = (float*)(smem + 34816 + 17408); // [128]

  const int bh = blockIdx.x;
  const int iT = 8 - blockIdx.y;          // heaviest tiles dispatch first
  const int tM = iT * 128;
  const int tid = threadIdx.x;
  const int wave = tid >> 6, lane = tid & 63;
  const int lr = lane & 15, quad = lane >> 4;
  const int waveM = (wave >> 1) * 64, waveN = (wave & 1) * 64;

  const ushort_t* Qg = qb + (size_t)bh * NPAD * DH;
  const ushort_t* Kg = kb + (size_t)bh * NPAD * DH;
  const ushort_t* Vg = vtb + (size_t)bh * DH * NPAD;
  float* attn_h = attn + (size_t)bh * ((size_t)SEQ_N * SEQ_N);

  // ---- stage Q once, keep as register fragments ----
#pragma unroll
  for (int p = 0; p < 4; ++p) {
    const int c = p * 256 + wave * 64 + lane;
    const int ks = c >> 9, n = (c >> 2) & 127, part = c & 3;
    gl_lds16(Qg + (size_t)(tM + n) * DH + ks * 32 + part * 8,
             lsQV + (size_t)(p * 256 + wave * 64) * 8);
  }
  __syncthreads();
  bf16x8 aq[4][2];
#pragma unroll
  for (int mi = 0; mi < 4; ++mi)
#pragma unroll
    for (int ks = 0; ks < 2; ++ks)
      aq[mi][ks] = *(const bf16x8*)(lsQV + ks * 4096 + (waveM + mi * 16 + lr) * 32 + quad * 8);
  __syncthreads();

  f32x4 acc[4][4];
  const f32x4 z4 = {0.f, 0.f, 0.f, 0.f};

  // ---- pass 1: row sums of exp ----
  float lsum[4][4];
#pragma unroll
  for (int mi = 0; mi < 4; ++mi)
#pragma unroll
    for (int r = 0; r < 4; ++r) lsum[mi][r] = 0.f;

  for (int j = 0; j <= iT; ++j) {
    __syncthreads();
#pragma unroll
    for (int p = 0; p < 4; ++p) {
      const int c = p * 256 + wave * 64 + lane;
      const int ks = c >> 9, n = (c >> 2) & 127, part = c & 3;
      gl_lds16(Kg + (size_t)(j * 128 + n) * DH + ks * 32 + part * 8,
               lsK + (size_t)(p * 256 + wave * 64) * 8);
    }
    __syncthreads();
#pragma unroll
    for (int mi = 0; mi < 4; ++mi)
#pragma unroll
      for (int ni = 0; ni < 4; ++ni) acc[mi][ni] = z4;
#pragma unroll
    for (int ks = 0; ks < 2; ++ks) {
      bf16x8 bk[4];
#pragma unroll
      for (int ni = 0; ni < 4; ++ni)
        bk[ni] = *(const bf16x8*)(lsK + ks * 4096 + (waveN + ni * 16 + lr) * 32 + quad * 8);
#pragma unroll
      for (int mi = 0; mi < 4; ++mi)
#pragma unroll
        for (int ni = 0; ni < 4; ++ni)
          acc[mi][ni] = __builtin_amdgcn_mfma_f32_16x16x32_bf16(aq[mi][ks], bk[ni], acc[mi][ni], 0, 0, 0);
    }
#pragma unroll
    for (int mi = 0; mi < 4; ++mi)
#pragma unroll
      for (int ni = 0; ni < 4; ++ni)
#pragma unroll
        for (int r = 0; r < 4; ++r) {
          const int row = tM + waveM + mi * 16 + quad * 4 + r;
          const int col = j * 128 + waveN + ni * 16 + lr;
          if (col <= row) lsum[mi][r] += __expf(acc[mi][ni][r] * 0.125f);
        }
  }
  // reduce across the 16 col-lanes, combine wave halves via LDS
#pragma unroll
  for (int mi = 0; mi < 4; ++mi)
#pragma unroll
    for (int r = 0; r < 4; ++r) {
      float s = lsum[mi][r];
      s += __shfl_xor(s, 1); s += __shfl_xor(s, 2);
      s += __shfl_xor(s, 4); s += __shfl_xor(s, 8);
      lsum[mi][r] = s;
    }
  __syncthreads();                // lsK reads done before lpart overwrites region0
  if (lr == 0) {
    const int wx = wave & 1;
#pragma unroll
    for (int mi = 0; mi < 4; ++mi)
#pragma unroll
      for (int r = 0; r < 4; ++r)
        lpart[wx * 128 + waveM + mi * 16 + quad * 4 + r] = lsum[mi][r];
  }
  __syncthreads();
  if (tid < 128) linvs[tid] = 1.0f / (lpart[tid] + lpart[128 + tid]);
  __syncthreads();
  float linv[4][4];
#pragma unroll
  for (int mi = 0; mi < 4; ++mi)
#pragma unroll
    for (int r = 0; r < 4; ++r)
      linv[mi][r] = linvs[waveM + mi * 16 + quad * 4 + r];

  // ---- pass 2: P write + PV ----
  f32x4 oacc[2][4];
#pragma unroll
  for (int i = 0; i < 2; ++i)
#pragma unroll
    for (int j = 0; j < 4; ++j) oacc[i][j] = z4;
  const int prow = wave * 32;             // O rows owned by this wave (PV A-op)
  const int wrow = wave * 32;             // rows this wave writes back to global
  const int lcol = lane;                  // 64 consecutive cols per store instr

  for (int j = 0; j <= iT; ++j) {
    __syncthreads();                      // prior iter's lsP/V reads complete
#pragma unroll
    for (int p = 0; p < 4; ++p) {
      const int c = p * 256 + wave * 64 + lane;
      const int ks = c >> 9, n = (c >> 2) & 127, part = c & 3;
      gl_lds16(Kg + (size_t)(j * 128 + n) * DH + ks * 32 + part * 8,
               lsK + (size_t)(p * 256 + wave * 64) * 8);
    }
    // V -> padded LDS [64][136]
#pragma unroll
    for (int p = 0; p < 4; ++p) {
      const int c = p * 256 + tid;
      const int n = c >> 4, klc = c & 15;
      const uint4 v = *(const uint4*)(Vg + (size_t)n * NPAD + j * 128 + klc * 8);
      *(uint4*)(lsQV + (size_t)n * 136 + klc * 8) = v;
    }
    __syncthreads();
#pragma unroll
    for (int mi = 0; mi < 4; ++mi)
#pragma unroll
      for (int ni = 0; ni < 4; ++ni) acc[mi][ni] = z4;
#pragma unroll
    for (int ks = 0; ks < 2; ++ks) {
      bf16x8 bk[4];
#pragma unroll
      for (int ni = 0; ni < 4; ++ni)
        bk[ni] = *(const bf16x8*)(lsK + ks * 4096 + (waveN + ni * 16 + lr) * 32 + quad * 8);
#pragma unroll
      for (int mi = 0; mi < 4; ++mi)
#pragma unroll
        for (int ni = 0; ni < 4; ++ni)
          acc[mi][ni] = __builtin_amdgcn_mfma_f32_16x16x32_bf16(aq[mi][ks], bk[ni], acc[mi][ni], 0, 0, 0);
    }
    __syncthreads();                      // all waves done reading lsK
#pragma unroll
    for (int mi = 0; mi < 4; ++mi)
#pragma unroll
      for (int ni = 0; ni < 4; ++ni)
#pragma unroll
        for (int r = 0; r < 4; ++r) {
          const int rowl = waveM + mi * 16 + quad * 4 + r;
          const int coll = waveN + ni * 16 + lr;
          const int row = tM + rowl;
          const int col = j * 128 + coll;
          const float pv = (col <= row) ? __expf(acc[mi][ni][r] * 0.125f) * linv[mi][r] : 0.f;
          lsP[(size_t)rowl * 136 + coll] = f2bf(pv);
        }
    __syncthreads();                      // lsP complete
    // PV MFMA
#pragma unroll
    for (int ks = 0; ks < 4; ++ks) {
      bf16x8 ap[2], bv[4];
#pragma unroll
      for (int mi2 = 0; mi2 < 2; ++mi2)
        ap[mi2] = *(const bf16x8*)(lsP + (size_t)(prow + mi2 * 16 + lr) * 136 + ks * 32 + quad * 8);
#pragma unroll
      for (int ni = 0; ni < 4; ++ni)
        bv[ni] = *(const bf16x8*)(lsQV + (size_t)(ni * 16 + lr) * 136 + ks * 32 + quad * 8);
#pragma unroll
      for (int mi2 = 0; mi2 < 2; ++mi2)
#pragma unroll
        for (int ni = 0; ni < 4; ++ni)
          oacc[mi2][ni] = __builtin_amdgcn_mfma_f32_16x16x32_bf16(ap[mi2], bv[ni], oacc[mi2][ni], 0, 0, 0);
    }
    // coalesced P write-back: per store instr, one row, 64 consecutive cols
#pragma unroll 8
    for (int rr = 0; rr < 32; ++rr) {
      const int grow = tM + wrow + rr;
      if (grow >= SEQ_N) break;           // wave-uniform
      const ushort_t* lrow = lsP + (size_t)(wrow + rr) * 136;
#pragma unroll
      for (int cb = 0; cb < 2; ++cb) {
        const int gcol = j * 128 + cb * 64 + lcol;
        union { unsigned u; float f; } cv;
        cv.u = ((unsigned)lrow[cb * 64 + lcol]) << 16;
        if (gcol < SEQ_N)
          __builtin_nontemporal_store(cv.f, attn_h + (size_t)grow * SEQ_N + gcol);
      }
    }
  }

  // ---- write O (bf16, token-major for proj GEMM) ----
  const int b_ = bh >> 4, h = bh & 15;
#pragma unroll
  for (int mi2 = 0; mi2 < 2; ++mi2)
#pragma unroll
    for (int ni = 0; ni < 4; ++ni)
#pragma unroll
      for (int r = 0; r < 4; ++r) {
        const int row = tM + prow + mi2 * 16 + quad * 4 + r;
        const int d = ni * 16 + lr;
        if (row < SEQ_N)
          ao[((size_t)row * 4 + b_) * CMODEL + h * DH + d] = f2bf(oacc[mi2][ni][r]);
      }

  // ---- zero strictly-upper attn region for these rows ----
  const int c0 = tM + 128;
  if (c0 <= 1024) {
    const int width = 1025 - c0;
    for (int r = wave; r < 128; r += 4) {
      float* rp = attn_h + (size_t)(tM + r) * SEQ_N + c0;
      int pre = ((16 - (int)(((uintptr_t)rp) & 15)) >> 2) & 3;
      if (pre > width) pre = width;
      for (int c = lane; c < pre; c += 64) rp[c] = 0.f;
      const int body = (width - pre) >> 2;
      f32x4* bp = (f32x4*)(rp + pre);
      const f32x4 zf4 = {0.f, 0.f, 0.f, 0.f};
      for (int c = lane; c < body; c += 64) __builtin_nontemporal_store(zf4, bp + c);
      for (int c = pre + body * 4 + lane; c < width; c += 64) rp[c] = 0.f;
    }
  }
}

// ---------------------------------------------------------------------------
extern "C" void kernel_launch(void* const* d_in, const int* in_sizes, int n_in,
                              void* d_out, int out_size, void* d_ws, size_t ws_size,
                              hipStream_t stream) {
  const float* x       = (const float*)d_in[0];
  const float* qkv_w   = (const float*)d_in[1];
  const float* proj_w  = (const float*)d_in[2];
  const float* proj_b  = (const float*)d_in[3];
  const float* ln1_g   = (const float*)d_in[4];
  const float* ln1_b   = (const float*)d_in[5];
  const float* ln2_g   = (const float*)d_in[6];
  const float* ln2_b   = (const float*)d_in[7];
  const float* fc_w    = (const float*)d_in[8];
  const float* fc_b    = (const float*)d_in[9];
  const float* cproj_w = (const float*)d_in[10];
  const float* cproj_b = (const float*)d_in[11];

  float* out_x = (float*)d_out;
  float* out_attn = out_x + (size_t)TTOK * CMODEL;

  char* p = (char*)d_ws;
  auto alloc = [&](size_t bytes) { char* r = p; p += (bytes + 255) & ~(size_t)255; return r; };
  ushort_t* ln1x  = (ushort_t*)alloc((size_t)MP * CMODEL * 2);
  ushort_t* wqkv  = (ushort_t*)alloc((size_t)3072 * 1024 * 2);
  ushort_t* wproj = (ushort_t*)alloc((size_t)1024 * 1024 * 2);
  ushort_t* wfc   = (ushort_t*)alloc((size_t)4096 * 1024 * 2);
  ushort_t* wcpr  = (ushort_t*)alloc((size_t)1024 * 4096 * 2);
  ushort_t* qb    = (ushort_t*)alloc((size_t)BH * NPAD * DH * 2);
  ushort_t* kb    = (ushort_t*)alloc((size_t)BH * NPAD * DH * 2);
  ushort_t* vtb   = (ushort_t*)alloc((size_t)BH * DH * NPAD * 2);
  ushort_t* aob   = (ushort_t*)alloc((size_t)MP * CMODEL * 2);
  float*    x1    = (float*)alloc((size_t)MP * CMODEL * 4);
  ushort_t* ln2x  = (ushort_t*)alloc((size_t)MP * CMODEL * 2);
  ushort_t* hb    = (ushort_t*)alloc((size_t)MP * 4096 * 2);
  (void)ws_size; (void)in_sizes; (void)n_in; (void)out_size;

  // weights -> bf16
  cvt_bf<<<3072, 256, 0, stream>>>(qkv_w, wqkv, 3072 * 1024);
  cvt_bf<<<1024, 256, 0, stream>>>(proj_w, wproj, 1024 * 1024);
  cvt_bf<<<4096, 256, 0, stream>>>(fc_w, wfc, 4096 * 1024);
  cvt_bf<<<4096, 256, 0, stream>>>(cproj_w, wcpr, 4096 * 1024);

  // ln1
  ln_bf<<<TTOK, 256, 0, stream>>>(x, ln1_g, ln1_b, ln1x);

  // qkv = ln1x @ qkv_w.T  -> scatter q/k/v^T bf16
  gemm_bt<0><<<dim3(24, 33, 1), 256, 0, stream>>>(ln1x, 1024, wqkv, 1024, 1024,
      nullptr, nullptr, nullptr, nullptr, qb, kb, vtb);

  // fused attention: logits+softmax+attn-write+PV
  attn_fused<<<dim3(64, 9), 256, 0, stream>>>(qb, kb, vtb, out_attn, aob);

  // proj + bias + residual -> x1 fp32
  gemm_bt<3><<<dim3(8, 33, 1), 256, 0, stream>>>(aob, 1024, wproj, 1024, 1024,
      proj_b, x, x1, nullptr, nullptr, nullptr, nullptr);

  // ln2
  ln_bf<<<TTOK, 256, 0, stream>>>(x1, ln2_g, ln2_b, ln2x);

  // fc + bias + quickGELU -> bf16
  gemm_bt<4><<<dim3(32, 33, 1), 256, 0, stream>>>(ln2x, 1024, wfc, 1024, 1024,
      fc_b, nullptr, nullptr, hb, nullptr, nullptr, nullptr);

  // cproj + bias + residual -> final x output
  gemm_bt<3><<<dim3(8, 33, 1), 256, 0, stream>>>(hb, 4096, wcpr, 4096, 4096,
      cproj_b, x1, out_x, nullptr, nullptr, nullptr, nullptr);
}